// Round 5
// baseline (278.105 us; speedup 1.0000x reference)
//
#include <hip/hip_runtime.h>

typedef _Float16 f16;
typedef __attribute__((ext_vector_type(8))) _Float16 half8;
typedef __attribute__((ext_vector_type(4))) float floatx4;
typedef __attribute__((ext_vector_type(4))) unsigned uint4v;

#define BB    16
#define TSN   16
#define NNP   4096
#define HID   64
#define KPK   224     // 6 k-tiles of 32 (h taps) + 1 k-tile (x taps + bias)
#define WOUT  128     // valid output positions per block
#define HALO  16      // time-halo for a single 16-step launch (R18)
#define WCMP  160     // computed rows per step = WOUT + 2*HALO (10 m-tiles)
#define HROWS 162     // h-buffer rows = WCMP + 2 (conv halo)
#define NMS   10
#define NTIL  32
#define XROWS (NNP + 2 * HALO)   // padded packed-x rows per (b,s)

#define LOG2E 1.44269504088896340736f

// LDS h layout: row stride 64 f16 (128 B == 0 mod 32 banks), 16B chunk
// XOR-swizzled by row (phys_chunk = chunk ^ (row&7)) -> b128 reads balanced,
// dword epilogue writes conflict-light. [verified R5: conflicts 8.3M -> 229K]
__device__ __forceinline__ int hadr(int rr, int c) {   // f16 index
    return rr * 64 + ((c ^ (rr & 7)) << 3);
}
__device__ __forceinline__ unsigned f16pair(float a, float b) {
    union { f16 h; unsigned short u; } ua, ub;
    ua.h = (f16)a; ub.h = (f16)b;
    return (unsigned)ua.u | ((unsigned)ub.u << 16);
}
// one-instruction f32x2 -> f16x2 pack (v_cvt_pkrtz_f16_f32).
__device__ __forceinline__ unsigned pkrtz(float a, float b) {
    typedef __fp16 h2v __attribute__((ext_vector_type(2)));
    h2v r = __builtin_amdgcn_cvt_pkrtz(a, b);
    union { h2v h; unsigned u; } cv; cv.h = r; return cv.u;
}

// Raw-rate transcendentals (no -ffast-math in harness). ~1 ulp each.
__device__ __forceinline__ float fast_exp2(float x) {
#if __has_builtin(__builtin_amdgcn_exp2f)
    return __builtin_amdgcn_exp2f(x);
#else
    return exp2f(x);
#endif
}
__device__ __forceinline__ float fast_rcp(float x) {
#if __has_builtin(__builtin_amdgcn_rcpf)
    return __builtin_amdgcn_rcpf(x);
#else
    return 1.0f / x;
#endif
}

// Lane exchanges via DPP (VALU) instead of ds_swizzle (DS pipe).
__device__ __forceinline__ float dpp_xor8(float v) {
    return __int_as_float(__builtin_amdgcn_mov_dpp(__float_as_int(v), 0x128, 0xF, 0xF, true));
}
__device__ __forceinline__ float dpp_xor1(float v) {
    return __int_as_float(__builtin_amdgcn_mov_dpp(__float_as_int(v), 0xB1, 0xF, 0xF, true));
}

// ---------------------------------------------------------------------------
// Pack conv_w (OIHW 256x65x3x3, only kw=1 live) -> f16 wpack[oc][k]:
//   k = kt*32+c;  kt<6: tap=kt>>1, ch j=(kt&1)*32+c;  kt=6: c<3 -> x tap c,
//   c==3 -> bias (paired with constant 1.0 in the x row slot; R15).
// Gate pre-scale folded in: i/f/o by -log2e, g by 2*log2e.
// ---------------------------------------------------------------------------
__global__ void pack_w_kernel(const float* __restrict__ conv_w,
                              const float* __restrict__ conv_b,
                              f16* __restrict__ wpack) {
    int idx = blockIdx.x * 256 + threadIdx.x;
    if (idx >= 4 * 64 * KPK) return;
    int k  = idx % KPK;
    int oc = idx / KPK;
    int kt = k >> 5, c = k & 31;
    float w = 0.0f;
    if (kt < 6) {
        int tap = kt >> 1;
        int j   = (kt & 1) * 32 + c;
        w = conv_w[((oc * 65 + 1 + j) * 3 + tap) * 3 + 1];
    } else if (c < 3) {
        w = conv_w[((oc * 65 + 0) * 3 + c) * 3 + 1];
    } else if (c == 3) {
        w = conv_b[oc];                       // bias folded into MFMA (R15)
    }
    float scale = (oc >= 192) ? (2.0f * LOG2E) : (-LOG2E);
    wpack[oc * KPK + k] = (f16)(w * scale);
}

// ---------------------------------------------------------------------------
// R19: pack x -> global xpack[b][s][XROWS] rows of 8 f16 (16B):
//   row pp <-> position p = pp - HALO;  {x[p-1], x[p], x[p+1], 1.0, 0,0,0,0}
// with per-component zero guards (identical semantics to the old LDS stage).
// lstm reads these rows with global_load_dwordx4 (L1/L2-resident), moving
// 10 of 80 DS ops/wave/step off the DS pipe (the largest pipe, ~40%).
// ---------------------------------------------------------------------------
__global__ void pack_x_kernel(const float* __restrict__ x, f16* __restrict__ xpack) {
    int idx = blockIdx.x * 256 + threadIdx.x;
    if (idx >= BB * TSN * XROWS) return;
    int pp = idx % XROWS;
    int bs = idx / XROWS;          // b*TSN + s
    int p  = pp - HALO;
    const float* xb = x + (size_t)bs * NNP;
    float v0 = (p - 1 >= 0 && p - 1 < NNP) ? xb[p - 1] : 0.0f;
    float v1 = (p >= 0 && p < NNP) ? xb[p] : 0.0f;
    float v2 = (p + 1 >= 0 && p + 1 < NNP) ? xb[p + 1] : 0.0f;
    uint4v q = { f16pair(v0, v1), f16pair(v2, 1.0f), 0u, 0u };
    *(uint4v*)(xpack + (size_t)idx * 8) = q;
}

// ---------------------------------------------------------------------------
// x-part MFMA: reads the packed-x row from GLOBAL (R19), seeds from zacc
// (bias folded via the 1.0 slot). xs is pre-offset to (b, s, n0).
// Issued one tile ahead of use by the ping-pong schedule -> latency hidden.
// ---------------------------------------------------------------------------
template <int MS>
__device__ __forceinline__ void do_mfx(
    const f16* __restrict__ xs, const half8 (&bf)[7][2],
    const floatx4& zacc, floatx4 (&acc)[2], int m)
{
    const int ar = MS * 16 + m;
    half8 a = *(const half8*)(xs + (size_t)ar * 8);
    acc[0] = __builtin_amdgcn_mfma_f32_16x16x32_f16(a, bf[6][0], zacc, 0, 0, 0);
    acc[1] = __builtin_amdgcn_mfma_f32_16x16x32_f16(a, bf[6][1], zacc, 0, 0, 0);
}

// h-part: 12 MFMA cluster wrapped in s_setprio(1) (T5).
template <int MS>
__device__ __forceinline__ void do_mfh(
    const f16* __restrict__ hrd, const half8 (&bf)[7][2],
    floatx4 (&acc)[2], int m, int kg)
{
    const int ar = MS * 16 + m;
    __builtin_amdgcn_s_setprio(1);
#pragma unroll
    for (int kt = 0; kt < 6; ++kt) {
        half8 a = *(const half8*)(hrd + hadr(ar + (kt >> 1), (kt & 1) * 4 + kg));
        acc[0] = __builtin_amdgcn_mfma_f32_16x16x32_f16(a, bf[kt][0], acc[0], 0, 0, 0);
        acc[1] = __builtin_amdgcn_mfma_f32_16x16x32_f16(a, bf[kt][1], acc[1], 0, 0, 0);
    }
    __builtin_amdgcn_s_setprio(0);
}

// ---------------------------------------------------------------------------
// Single-tile epilogue: gate exchange (DPP), LSTM pointwise, h write.
// R15: rcp-fusion — 7 trans ops per element.
// R16: batched trans — 8 independent v_exp issue before dependent algebra.
// ---------------------------------------------------------------------------
template <int MS>
__device__ __forceinline__ void do_epi(
    f16* __restrict__ hwr, floatx4 (&acc)[2], float (&creg)[NMS * 2],
    int m, int kg, int wave, bool lowm, bool edge, int n0)
{
    float pg[2][2];
#pragma unroll
    for (int q = 0; q < 2; ++q)
#pragma unroll
        for (int j = 0; j < 2; ++j) {
            float send = lowm ? acc[q][2 + j] : acc[q][j];
            pg[q][j] = dpp_xor8(send);
        }

    // gate pre-activations, both elements: [j][i,f,o,g]
    float Y[2][4];
#pragma unroll
    for (int j = 0; j < 2; ++j) {
        Y[j][0] = lowm ? acc[0][j] : pg[0][j];
        Y[j][1] = lowm ? pg[0][j] : acc[0][2 + j];
        Y[j][2] = lowm ? acc[1][j] : pg[1][j];
        Y[j][3] = lowm ? pg[1][j] : acc[1][2 + j];
    }
    // 8 independent exps back-to-back (trans pipe fill)
    float E[2][4];
#pragma unroll
    for (int j = 0; j < 2; ++j)
#pragma unroll
        for (int g = 0; g < 4; ++g) E[j][g] = fast_exp2(Y[j][g]);

#pragma unroll
    for (int j = 0; j < 2; ++j) {
        int r  = lowm ? j : 2 + j;
        float Fi = 1.0f + E[j][0], Ff = 1.0f + E[j][1];
        float Fo = 1.0f + E[j][2], Fg = 1.0f + E[j][3];
        const int ridx = MS * 2 + j;
        float P  = Fi * Fg;
        float N  = fmaf(E[j][3] - 1.0f, Ff, creg[ridx] * P);
        float cn = N * fast_rcp(P * Ff);          // sig(f)*c + sig(i)*tanh(g)
        float Ec = fast_exp2(cn * (2.0f * LOG2E));
        float hnf = (Ec - 1.0f) * fast_rcp(Fo * (1.0f + Ec));  // sig(o)*tanh(cn)
        creg[ridx] = cn;
        int rit = MS * 16 + kg * 4 + r;        // compute-window row
        if (edge) {
            int pos = n0 - HALO + rit;
            if (pos < 0 || pos >= NNP) hnf = 0.0f;  // zero-pad semantics
        }
        float po = dpp_xor1(hnf);               // partner hid^1
        if (!(m & 1)) {                          // even lane packs dword
            int rr = rit + 1;
            ((unsigned*)hwr)[rr * 32 + ((wave ^ (rr & 7)) << 2) + ((m & 7) >> 1)] =
                pkrtz(hnf, po);
        }
    }
}

// ---------------------------------------------------------------------------
// ConvLSTM, ALL 16 steps in ONE launch (R18), 512 independent blocks.
// Block = 512 thr (8 waves). Gate-packed MFMA N-dim (R9); DPP exchange (R13);
// halo-16 recompute; c in registers; fc fused into the drain.
// R19: x moved OFF the DS pipe — packed-x rows read from global (L1/L2)
// instead of LDS (DS was the largest pipe at ~40%); xt LDS buffer, the
// 8-step restage and its double barrier are gone (LDS 62 -> 41.5 KB).
// R17 lesson: occupancy is VGPR-capped (4 waves/SIMD at <=128 VGPR);
// keep launch_bounds(512,2) and stay under 128 VGPR.
// ---------------------------------------------------------------------------
__global__ __launch_bounds__(512, 2)
void lstm_kernel(const f16* __restrict__ xpack, const f16* __restrict__ wpack,
                 const float* __restrict__ fc_w, const float* __restrict__ fc_b,
                 float* __restrict__ out)
{
    __shared__ __align__(16) f16 hlds[2][HROWS * 64];

    const int blk  = blockIdx.x;
    const int b    = blk >> 5;
    const int tau  = blk & 31;
    const int n0   = tau * WOUT;
    const int tid  = threadIdx.x;
    const int lane = tid & 63;
    const int wave = tid >> 6;             // 0..7
    const int m    = lane & 15;
    const int kg   = lane >> 4;
    const int gh   = m >> 3;               // gate half of this lane's column
    const int hid  = wave * 8 + (m & 7);
    const bool lowm = (m < 8);
    const bool edge = (tau == 0) || (tau == NTIL - 1);

    // B fragments, gate-packed: 14 half8 = 56 VGPR, resident all 16 steps.
    half8 bf[7][2];
#pragma unroll
    for (int kt = 0; kt < 7; ++kt)
#pragma unroll
        for (int q = 0; q < 2; ++q)
            bf[kt][q] = *(const half8*)(wpack + (size_t)((q * 2 + gh) * 64 + hid) * KPK + kt * 32 + kg * 8);

    const floatx4 zacc = {0.0f, 0.0f, 0.0f, 0.0f};   // persistent MFMA C seed

    float creg[NMS * 2];
#pragma unroll
    for (int i = 0; i < NMS * 2; ++i) creg[i] = 0.0f;

    // h(0) = 0; rows 0 / HROWS-1 of both buffers stay 0 forever (conv halo).
    for (int i = tid; i < HROWS * 64; i += 512) { hlds[0][i] = (f16)0; hlds[1][i] = (f16)0; }

    // packed-x base for this block: row pp = n0 + r  (HALO folds out exactly)
    const f16* xp0 = xpack + ((size_t)b * TSN * XROWS + n0) * 8;

#pragma unroll 1
    for (int s = 0; s < TSN; ++s) {
        const f16* hrd = hlds[s & 1];
        f16*       hwr = hlds[(s & 1) ^ 1];
        const f16* xs  = xp0 + (size_t)s * XROWS * 8;

        floatx4 accA[2], accB[2];
#define MFX(MS, A) do_mfx<MS>(xs, bf, zacc, A, m)
#define MFH(MS, A) do_mfh<MS>(hrd, bf, A, m, kg)
#define MFF(MS, A) do { MFX(MS, A); MFH(MS, A); } while (0)
#define EP(MS, A)  do_epi<MS>(hwr, A, creg, m, kg, wave, lowm, edge, n0)
        // pre-barrier: x-part of the first two tiles (global reads, no LDS
        // dependency — fills the barrier wait with matrix work)
        if (wave < 4) { MFX(0, accA); MFX(1, accB); }
        else          { MFX(5, accA); MFX(6, accB); }

        __syncthreads();   // step s's h reads vs step s-1's h writes (+ init)

        if (wave < 4) {
            MFH(0, accA);
            MFH(1, accB); EP(0, accA);
            MFF(2, accA); EP(1, accB);
            MFF(3, accB); EP(2, accA);
            MFF(4, accA); EP(3, accB);
            MFF(5, accB); EP(4, accA);
            MFF(6, accA); EP(5, accB);
            MFF(7, accB); EP(6, accA);
            MFF(8, accA); EP(7, accB);
            MFF(9, accB); EP(8, accA);
            EP(9, accB);
        } else {
            MFH(5, accA);
            MFH(6, accB); EP(5, accA);
            MFF(7, accA); EP(6, accB);
            MFF(8, accB); EP(7, accA);
            MFF(9, accA); EP(8, accB);
            MFF(0, accB); EP(9, accA);
            MFF(1, accA); EP(0, accB);
            MFF(2, accB); EP(1, accA);
            MFF(3, accA); EP(2, accB);
            MFF(4, accB); EP(3, accA);
            EP(4, accB);
        }
#undef MFX
#undef MFH
#undef MFF
#undef EP
    }
    __syncthreads();   // step-15 h writes complete (last write buffer = hlds[0])

    // ---- fused fc drain: out[b,t,n0+row] = dot(h[row,:], fc_w) + fc_b ----
    // 4 threads per row, 16 hid each; shuffle-reduce; LDS bounce for coalesced
    // stores (hlds[1] is dead — reuse as float scratch).
    {
        const int part = tid & 3, row = tid >> 2;      // row in [0,128)
        float fw[16];
#pragma unroll
        for (int e = 0; e < 16; ++e) fw[e] = fc_w[part * 16 + e];
        const int rr = row + HALO + 1;                 // valid window row
        float ssum = 0.0f;
#pragma unroll
        for (int cc = 0; cc < 2; ++cc) {
            half8 v = *(const half8*)(hlds[0] + hadr(rr, part * 2 + cc));
#pragma unroll
            for (int e = 0; e < 8; ++e) ssum += (float)v[e] * fw[cc * 8 + e];
        }
        ssum += __shfl_xor(ssum, 1);
        ssum += __shfl_xor(ssum, 2);
        float* srow = (float*)hlds[1];
        if (part == 0) srow[row] = ssum + fc_b[0];
        __syncthreads();
        for (int i = tid; i < WOUT * TSN; i += 512) {
            int tt = i >> 7, r2 = i & (WOUT - 1);
            out[((size_t)b * TSN + tt) * NNP + n0 + r2] = srow[r2];
        }
    }
}

extern "C" void kernel_launch(void* const* d_in, const int* in_sizes, int n_in,
                              void* d_out, int out_size, void* d_ws, size_t ws_size,
                              hipStream_t stream) {
    const float* x      = (const float*)d_in[0];
    const float* conv_w = (const float*)d_in[1];
    const float* conv_b = (const float*)d_in[2];
    const float* fc_w   = (const float*)d_in[3];
    const float* fc_b   = (const float*)d_in[4];
    float* out = (float*)d_out;

    char* ws = (char*)d_ws;
    f16* wpack = (f16*)ws;                               // 112 KiB
    f16* xpack = (f16*)(ws + 131072);                    // 16.9 MB

    pack_w_kernel<<<(4 * 64 * KPK + 255) / 256, 256, 0, stream>>>(conv_w, conv_b, wpack);
    pack_x_kernel<<<(BB * TSN * XROWS + 255) / 256, 256, 0, stream>>>(x, xpack);
    lstm_kernel<<<BB * NTIL, 512, 0, stream>>>(xpack, wpack, fc_w, fc_b, out);
}

// Round 6
// 234.384 us; speedup vs baseline: 1.1865x; 1.1865x over previous
//
#include <hip/hip_runtime.h>

typedef _Float16 f16;
typedef __attribute__((ext_vector_type(8))) _Float16 half8;
typedef __attribute__((ext_vector_type(4))) float floatx4;

#define BB    16
#define TSN   16
#define NNP   4096
#define HID   64
#define KPK   224     // 6 k-tiles of 32 (h taps) + 1 k-tile (x taps + bias)
#define WOUT  128     // valid output positions per block
#define HALO  16      // time-halo for a single 16-step launch (R18)
#define WCMP  160     // computed rows per step = WOUT + 2*HALO (10 m-tiles)
#define HROWS 162     // h-buffer rows = WCMP + 2 (conv halo)
#define NMS   10
#define NTIL  32

#define LOG2E 1.44269504088896340736f

// LDS h layout: row stride 64 f16 (128 B == 0 mod 32 banks), 16B chunk
// XOR-swizzled by row (phys_chunk = chunk ^ (row&7)) -> b128 reads balanced,
// dword epilogue writes conflict-light. [verified R5: conflicts 8.3M -> 229K]
__device__ __forceinline__ int hadr(int rr, int c) {   // f16 index
    return rr * 64 + ((c ^ (rr & 7)) << 3);
}
__device__ __forceinline__ unsigned f16pair(float a, float b) {
    union { f16 h; unsigned short u; } ua, ub;
    ua.h = (f16)a; ub.h = (f16)b;
    return (unsigned)ua.u | ((unsigned)ub.u << 16);
}
// one-instruction f32x2 -> f16x2 pack (v_cvt_pkrtz_f16_f32).
__device__ __forceinline__ unsigned pkrtz(float a, float b) {
    typedef __fp16 h2v __attribute__((ext_vector_type(2)));
    h2v r = __builtin_amdgcn_cvt_pkrtz(a, b);
    union { h2v h; unsigned u; } cv; cv.h = r; return cv.u;
}

// Raw-rate transcendentals (no -ffast-math in harness). ~1 ulp each.
__device__ __forceinline__ float fast_exp2(float x) {
#if __has_builtin(__builtin_amdgcn_exp2f)
    return __builtin_amdgcn_exp2f(x);
#else
    return exp2f(x);
#endif
}
__device__ __forceinline__ float fast_rcp(float x) {
#if __has_builtin(__builtin_amdgcn_rcpf)
    return __builtin_amdgcn_rcpf(x);
#else
    return 1.0f / x;
#endif
}

// Lane exchanges via DPP (VALU) instead of ds_swizzle (DS pipe).
__device__ __forceinline__ float dpp_xor8(float v) {
    return __int_as_float(__builtin_amdgcn_mov_dpp(__float_as_int(v), 0x128, 0xF, 0xF, true));
}
__device__ __forceinline__ float dpp_xor1(float v) {
    return __int_as_float(__builtin_amdgcn_mov_dpp(__float_as_int(v), 0xB1, 0xF, 0xF, true));
}

// ---------------------------------------------------------------------------
// Pack conv_w (OIHW 256x65x3x3, only kw=1 live) -> f16 wpack[oc][k]:
//   k = kt*32+c;  kt<6: tap=kt>>1, ch j=(kt&1)*32+c;  kt=6: c<3 -> x tap c,
//   c==3 -> bias (paired with constant 1.0 in the x k-slot; R15).
// Gate pre-scale folded in: i/f/o by -log2e, g by 2*log2e.
// ---------------------------------------------------------------------------
__global__ void pack_w_kernel(const float* __restrict__ conv_w,
                              const float* __restrict__ conv_b,
                              f16* __restrict__ wpack) {
    int idx = blockIdx.x * 256 + threadIdx.x;
    if (idx >= 4 * 64 * KPK) return;
    int k  = idx % KPK;
    int oc = idx / KPK;
    int kt = k >> 5, c = k & 31;
    float w = 0.0f;
    if (kt < 6) {
        int tap = kt >> 1;
        int j   = (kt & 1) * 32 + c;
        w = conv_w[((oc * 65 + 1 + j) * 3 + tap) * 3 + 1];
    } else if (c < 3) {
        w = conv_w[((oc * 65 + 0) * 3 + c) * 3 + 1];
    } else if (c == 3) {
        w = conv_b[oc];                       // bias folded into MFMA (R15)
    }
    float scale = (oc >= 192) ? (2.0f * LOG2E) : (-LOG2E);
    wpack[oc * KPK + k] = (f16)(w * scale);
}

// ---------------------------------------------------------------------------
// x-part MFMA: reads the step's pre-staged xt row from LDS (R20: back to LDS
// after R19's global-read regression), seeds from zacc (bias via 1.0 slot).
// ---------------------------------------------------------------------------
template <int MS>
__device__ __forceinline__ void do_mfx(
    const f16* __restrict__ xts, const half8 (&bf)[7][2],
    const floatx4& zacc, floatx4 (&acc)[2], int m)
{
    const int ar = MS * 16 + m;
    half8 a = *(const half8*)(xts + ar * 8);
    acc[0] = __builtin_amdgcn_mfma_f32_16x16x32_f16(a, bf[6][0], zacc, 0, 0, 0);
    acc[1] = __builtin_amdgcn_mfma_f32_16x16x32_f16(a, bf[6][1], zacc, 0, 0, 0);
}

// h-part: 12 MFMA cluster. R20: setprio dropped (R15 vs R17 A/B showed it
// consistently ~2 us negative on this lockstep-ish structure).
template <int MS>
__device__ __forceinline__ void do_mfh(
    const f16* __restrict__ hrd, const half8 (&bf)[7][2],
    floatx4 (&acc)[2], int m, int kg)
{
    const int ar = MS * 16 + m;
#pragma unroll
    for (int kt = 0; kt < 6; ++kt) {
        half8 a = *(const half8*)(hrd + hadr(ar + (kt >> 1), (kt & 1) * 4 + kg));
        acc[0] = __builtin_amdgcn_mfma_f32_16x16x32_f16(a, bf[kt][0], acc[0], 0, 0, 0);
        acc[1] = __builtin_amdgcn_mfma_f32_16x16x32_f16(a, bf[kt][1], acc[1], 0, 0, 0);
    }
}

// ---------------------------------------------------------------------------
// Single-tile epilogue: gate exchange (DPP), LSTM pointwise, h write.
// R15: rcp-fusion — 7 trans ops per element.
// R16: batched trans — 8 independent v_exp issue before dependent algebra.
// ---------------------------------------------------------------------------
template <int MS>
__device__ __forceinline__ void do_epi(
    f16* __restrict__ hwr, floatx4 (&acc)[2], float (&creg)[NMS * 2],
    int m, int kg, int wave, bool lowm, bool edge, int n0)
{
    float pg[2][2];
#pragma unroll
    for (int q = 0; q < 2; ++q)
#pragma unroll
        for (int j = 0; j < 2; ++j) {
            float send = lowm ? acc[q][2 + j] : acc[q][j];
            pg[q][j] = dpp_xor8(send);
        }

    // gate pre-activations, both elements: [j][i,f,o,g]
    float Y[2][4];
#pragma unroll
    for (int j = 0; j < 2; ++j) {
        Y[j][0] = lowm ? acc[0][j] : pg[0][j];
        Y[j][1] = lowm ? pg[0][j] : acc[0][2 + j];
        Y[j][2] = lowm ? acc[1][j] : pg[1][j];
        Y[j][3] = lowm ? pg[1][j] : acc[1][2 + j];
    }
    // 8 independent exps back-to-back (trans pipe fill)
    float E[2][4];
#pragma unroll
    for (int j = 0; j < 2; ++j)
#pragma unroll
        for (int g = 0; g < 4; ++g) E[j][g] = fast_exp2(Y[j][g]);

#pragma unroll
    for (int j = 0; j < 2; ++j) {
        int r  = lowm ? j : 2 + j;
        float Fi = 1.0f + E[j][0], Ff = 1.0f + E[j][1];
        float Fo = 1.0f + E[j][2], Fg = 1.0f + E[j][3];
        const int ridx = MS * 2 + j;
        float P  = Fi * Fg;
        float N  = fmaf(E[j][3] - 1.0f, Ff, creg[ridx] * P);
        float cn = N * fast_rcp(P * Ff);          // sig(f)*c + sig(i)*tanh(g)
        float Ec = fast_exp2(cn * (2.0f * LOG2E));
        float hnf = (Ec - 1.0f) * fast_rcp(Fo * (1.0f + Ec));  // sig(o)*tanh(cn)
        creg[ridx] = cn;
        int rit = MS * 16 + kg * 4 + r;        // compute-window row
        if (edge) {
            int pos = n0 - HALO + rit;
            if (pos < 0 || pos >= NNP) hnf = 0.0f;  // zero-pad semantics
        }
        float po = dpp_xor1(hnf);               // partner hid^1
        if (!(m & 1)) {                          // even lane packs dword
            int rr = rit + 1;
            ((unsigned*)hwr)[rr * 32 + ((wave ^ (rr & 7)) << 2) + ((m & 7) >> 1)] =
                pkrtz(hnf, po);
        }
    }
}

// ---------------------------------------------------------------------------
// ConvLSTM, ALL 16 steps in ONE launch (R18), 512 independent blocks.
// Block = 512 thr (8 waves). Gate-packed MFMA N-dim (R9); DPP exchange (R13);
// halo-16 recompute; c in registers; fc fused into the drain; x staged in
// LDS 8 steps at a time (R20: reverted from R19's global x — global latency
// in the acc chain regressed 224->244 us).
// R20 work trims (provable, no scheduling speculation):
//  - step 0 is x-only (h(0)=0: skip all h-MFMAs and h ds_reads)
//  - step 15 computes only tiles 1..8 (output window rit in [16,144))
//  - LDS init: only the 4 conv-halo rows (step 0 writes everything else)
// R17 lesson: occupancy is VGPR-capped; launch_bounds(512,2), stay <128 VGPR.
// ---------------------------------------------------------------------------
__global__ __launch_bounds__(512, 2)
void lstm_kernel(const float* __restrict__ x, const f16* __restrict__ wpack,
                 const float* __restrict__ fc_w, const float* __restrict__ fc_b,
                 float* __restrict__ out)
{
    __shared__ __align__(16) f16 hlds[2][HROWS * 64];
    __shared__ __align__(16) f16 xt[8 * WCMP * 8];

    const int blk  = blockIdx.x;
    const int b    = blk >> 5;
    const int tau  = blk & 31;
    const int n0   = tau * WOUT;
    const int tid  = threadIdx.x;
    const int lane = tid & 63;
    const int wave = tid >> 6;             // 0..7
    const int m    = lane & 15;
    const int kg   = lane >> 4;
    const int gh   = m >> 3;               // gate half of this lane's column
    const int hid  = wave * 8 + (m & 7);
    const bool lowm = (m < 8);
    const bool edge = (tau == 0) || (tau == NTIL - 1);

    // B fragments, gate-packed: 14 half8 = 56 VGPR, resident all 16 steps.
    half8 bf[7][2];
#pragma unroll
    for (int kt = 0; kt < 7; ++kt)
#pragma unroll
        for (int q = 0; q < 2; ++q)
            bf[kt][q] = *(const half8*)(wpack + (size_t)((q * 2 + gh) * 64 + hid) * KPK + kt * 32 + kg * 8);

    const floatx4 zacc = {0.0f, 0.0f, 0.0f, 0.0f};   // persistent MFMA C seed

    float creg[NMS * 2];
#pragma unroll
    for (int i = 0; i < NMS * 2; ++i) creg[i] = 0.0f;

    // ---- stage 8 steps of x into xt (slot3 = 1.0 pairs with bias) ----
    auto stage_x = [&](int base) {
        for (int i = tid; i < 8 * WCMP; i += 512) {
            int ss = i / WCMP, r = i - ss * WCMP;
            const float* xb = x + ((size_t)b * TSN + base + ss) * NNP;
            int p = n0 - HALO + r;
            float v0 = (p - 1 >= 0 && p - 1 < NNP) ? xb[p - 1] : 0.0f;
            float v1 = (p >= 0 && p < NNP) ? xb[p] : 0.0f;
            float v2 = (p + 1 >= 0 && p + 1 < NNP) ? xb[p + 1] : 0.0f;
            unsigned* q = (unsigned*)(xt + (size_t)i * 8);
            q[0] = f16pair(v0, v1);
            q[1] = f16pair(v2, 1.0f);
            q[2] = 0u; q[3] = 0u;
        }
    };
    stage_x(0);

    // R20: only the conv-halo rows (0 and HROWS-1) of both buffers need
    // zeroing — every other read row is written by the preceding step.
    for (int i = tid; i < 4 * 64; i += 512) {
        int buf = i >> 7, rr = ((i >> 6) & 1) ? (HROWS - 1) : 0;
        hlds[buf][rr * 64 + (i & 63)] = (f16)0;
    }

    __syncthreads();   // staging + halo-init visible to step 0

    // ---- step 0: x-only (h(0)=0 => gates = W_x*x + b), writes hlds[1] ----
    {
        f16* hwr = hlds[1];
        const f16* xts = xt;
        floatx4 accA[2], accB[2];
#define MFX(MS, A) do_mfx<MS>(xts, bf, zacc, A, m)
#define EP(MS, A)  do_epi<MS>(hwr, A, creg, m, kg, wave, lowm, edge, n0)
        MFX(0, accA);
        MFX(1, accB); EP(0, accA);
        MFX(2, accA); EP(1, accB);
        MFX(3, accB); EP(2, accA);
        MFX(4, accA); EP(3, accB);
        MFX(5, accB); EP(4, accA);
        MFX(6, accA); EP(5, accB);
        MFX(7, accB); EP(6, accA);
        MFX(8, accA); EP(7, accB);
        MFX(9, accB); EP(8, accA);
        EP(9, accB);
#undef MFX
#undef EP
    }

#pragma unroll 1
    for (int s = 1; s < TSN - 1; ++s) {
        if (s == 8) {
            __syncthreads();   // all step-7 xt reads complete before overwrite
            stage_x(8);
        }
        __syncthreads();   // step s's h reads vs step s-1's h writes (+ restage)

        const f16* hrd = hlds[s & 1];
        f16*       hwr = hlds[(s & 1) ^ 1];
        const f16* xts = xt + (size_t)(s & 7) * WCMP * 8;

        floatx4 accA[2], accB[2];
#define MFF(MS, A) do { do_mfx<MS>(xts, bf, zacc, A, m); do_mfh<MS>(hrd, bf, A, m, kg); } while (0)
#define EP(MS, A)  do_epi<MS>(hwr, A, creg, m, kg, wave, lowm, edge, n0)
        if (wave < 4) {
            MFF(0, accA);
            MFF(1, accB); EP(0, accA);
            MFF(2, accA); EP(1, accB);
            MFF(3, accB); EP(2, accA);
            MFF(4, accA); EP(3, accB);
            MFF(5, accB); EP(4, accA);
            MFF(6, accA); EP(5, accB);
            MFF(7, accB); EP(6, accA);
            MFF(8, accA); EP(7, accB);
            MFF(9, accB); EP(8, accA);
            EP(9, accB);
        } else {
            MFF(5, accA);
            MFF(6, accB); EP(5, accA);
            MFF(7, accA); EP(6, accB);
            MFF(8, accB); EP(7, accA);
            MFF(9, accA); EP(8, accB);
            MFF(0, accB); EP(9, accA);
            MFF(1, accA); EP(0, accB);
            MFF(2, accB); EP(1, accA);
            MFF(3, accA); EP(2, accB);
            MFF(4, accB); EP(3, accA);
            EP(4, accB);
        }
#undef MFF
#undef EP
    }

    // ---- step 15: only tiles 1..8 (output window rit in [16,144)) ----
    {
        __syncthreads();   // step-15 reads (hlds[1]) vs step-14 writes
        const f16* hrd = hlds[1];
        f16*       hwr = hlds[0];
        const f16* xts = xt + (size_t)7 * WCMP * 8;

        floatx4 accA[2], accB[2];
#define MFF(MS, A) do { do_mfx<MS>(xts, bf, zacc, A, m); do_mfh<MS>(hrd, bf, A, m, kg); } while (0)
#define EP(MS, A)  do_epi<MS>(hwr, A, creg, m, kg, wave, lowm, edge, n0)
        if (wave < 4) {
            MFF(1, accA);
            MFF(2, accB); EP(1, accA);
            MFF(3, accA); EP(2, accB);
            MFF(4, accB); EP(3, accA);
            MFF(5, accA); EP(4, accB);
            MFF(6, accB); EP(5, accA);
            MFF(7, accA); EP(6, accB);
            MFF(8, accB); EP(7, accA);
            EP(8, accB);
        } else {
            MFF(5, accA);
            MFF(6, accB); EP(5, accA);
            MFF(7, accA); EP(6, accB);
            MFF(8, accB); EP(7, accA);
            MFF(1, accA); EP(8, accB);
            MFF(2, accB); EP(1, accA);
            MFF(3, accA); EP(2, accB);
            MFF(4, accB); EP(3, accA);
            EP(4, accB);
        }
#undef MFF
#undef EP
    }
    __syncthreads();   // step-15 h writes complete (write buffer = hlds[0])

    // ---- fused fc drain: out[b,t,n0+row] = dot(h[row,:], fc_w) + fc_b ----
    // 4 threads per row, 16 hid each; shuffle-reduce; LDS bounce for coalesced
    // stores (xt is dead — reuse as float scratch).
    {
        const int part = tid & 3, row = tid >> 2;      // row in [0,128)
        float fw[16];
#pragma unroll
        for (int e = 0; e < 16; ++e) fw[e] = fc_w[part * 16 + e];
        const int rr = row + HALO + 1;                 // valid window row
        float ssum = 0.0f;
#pragma unroll
        for (int cc = 0; cc < 2; ++cc) {
            half8 v = *(const half8*)(hlds[0] + hadr(rr, part * 2 + cc));
#pragma unroll
            for (int e = 0; e < 8; ++e) ssum += (float)v[e] * fw[cc * 8 + e];
        }
        ssum += __shfl_xor(ssum, 1);
        ssum += __shfl_xor(ssum, 2);
        float* srow = (float*)xt;
        if (part == 0) srow[row] = ssum + fc_b[0];
        __syncthreads();
        for (int i = tid; i < WOUT * TSN; i += 512) {
            int tt = i >> 7, r2 = i & (WOUT - 1);
            out[((size_t)b * TSN + tt) * NNP + n0 + r2] = srow[r2];
        }
    }
}

extern "C" void kernel_launch(void* const* d_in, const int* in_sizes, int n_in,
                              void* d_out, int out_size, void* d_ws, size_t ws_size,
                              hipStream_t stream) {
    const float* x      = (const float*)d_in[0];
    const float* conv_w = (const float*)d_in[1];
    const float* conv_b = (const float*)d_in[2];
    const float* fc_w   = (const float*)d_in[3];
    const float* fc_b   = (const float*)d_in[4];
    float* out = (float*)d_out;

    f16* wpack = (f16*)d_ws;                                        // 112 KiB

    pack_w_kernel<<<(4 * 64 * KPK + 255) / 256, 256, 0, stream>>>(conv_w, conv_b, wpack);
    lstm_kernel<<<BB * NTIL, 512, 0, stream>>>(x, wpack, fc_w, fc_b, out);
}

// Round 9
// 213.271 us; speedup vs baseline: 1.3040x; 1.0990x over previous
//
#include <hip/hip_runtime.h>

typedef _Float16 f16;
typedef __attribute__((ext_vector_type(8))) _Float16 half8;
typedef __attribute__((ext_vector_type(4))) float floatx4;

#define BB    16
#define TSN   16
#define NNP   4096
#define HID   64
#define KPK   224     // 6 k-tiles of 32 (h taps) + 1 k-tile (x taps + bias)
#define WOUT  128     // valid output positions per block
#define HALO  16      // time-halo for a single 16-step launch (R18)
#define WCMP  160     // computed rows per step = WOUT + 2*HALO (10 m-tiles)
#define HROWS 162     // h-buffer rows = WCMP + 2 (conv halo)
#define NMS   10
#define NTIL  32

#define LOG2E 1.44269504088896340736f

// LDS h layout: row stride 64 f16 (128 B == 0 mod 32 banks), 16B chunk
// XOR-swizzled by row (phys_chunk = chunk ^ (row&7)) -> b128 reads balanced,
// epilogue writes conflict-light. [verified R5: conflicts 8.3M -> 229K]
__device__ __forceinline__ int hadr(int rr, int c) {   // f16 index
    return rr * 64 + ((c ^ (rr & 7)) << 3);
}
__device__ __forceinline__ unsigned f16pair(float a, float b) {
    union { f16 h; unsigned short u; } ua, ub;
    ua.h = (f16)a; ub.h = (f16)b;
    return (unsigned)ua.u | ((unsigned)ub.u << 16);
}

// Raw-rate transcendentals (no -ffast-math in harness). ~1 ulp each.
__device__ __forceinline__ float fast_exp2(float x) {
#if __has_builtin(__builtin_amdgcn_exp2f)
    return __builtin_amdgcn_exp2f(x);
#else
    return exp2f(x);
#endif
}
__device__ __forceinline__ float fast_rcp(float x) {
#if __has_builtin(__builtin_amdgcn_rcpf)
    return __builtin_amdgcn_rcpf(x);
#else
    return 1.0f / x;
#endif
}

// R22/R23: one-instruction masked partner-select.
// update_dpp(old, src, ROW_ROR:8, row=0xF, bank): lanes enabled by BANK mask
// receive DPP(src) from partner lane^8 (ROR8 == pairwise swap within the
// 16-lane row); disabled lanes keep old. The two sides of the pair use
// DIFFERENT registers (R21 bug fixed in R22). R23: BANK must be a
// compile-time constant -> template parameter.
//   BANK=0xC (lanes 8-15 active): high lanes get partner's src, low keep old.
//   BANK=0x3 (lanes 0-7  active): low lanes get partner's src, high keep old.
template <int BANK>
__device__ __forceinline__ float sel2(float old_v, float src_v) {
    return __int_as_float(__builtin_amdgcn_update_dpp(
        __float_as_int(old_v), __float_as_int(src_v), 0x128, 0xF, BANK, false));
}

// ---------------------------------------------------------------------------
// Pack conv_w (OIHW 256x65x3x3, only kw=1 live) -> f16 wpack[oc][k]:
//   k = kt*32+c;  kt<6: tap=kt>>1, ch j=(kt&1)*32+c;  kt=6: c<3 -> x tap c,
//   c==3 -> bias (paired with constant 1.0 in the x k-slot; R15).
// Gate pre-scale folded in: i/f/o by -log2e, g by 2*log2e.
// ---------------------------------------------------------------------------
__global__ void pack_w_kernel(const float* __restrict__ conv_w,
                              const float* __restrict__ conv_b,
                              f16* __restrict__ wpack) {
    int idx = blockIdx.x * 256 + threadIdx.x;
    if (idx >= 4 * 64 * KPK) return;
    int k  = idx % KPK;
    int oc = idx / KPK;
    int kt = k >> 5, c = k & 31;
    float w = 0.0f;
    if (kt < 6) {
        int tap = kt >> 1;
        int j   = (kt & 1) * 32 + c;
        w = conv_w[((oc * 65 + 1 + j) * 3 + tap) * 3 + 1];
    } else if (c < 3) {
        w = conv_w[((oc * 65 + 0) * 3 + c) * 3 + 1];
    } else if (c == 3) {
        w = conv_b[oc];                       // bias folded into MFMA (R15)
    }
    float scale = (oc >= 192) ? (2.0f * LOG2E) : (-LOG2E);
    wpack[oc * KPK + k] = (f16)(w * scale);
}

// ---------------------------------------------------------------------------
// x-part MFMA: reads the step's pre-staged xt row from LDS, seeds from zacc
// (bias via the 1.0 slot).
// ---------------------------------------------------------------------------
template <int MS>
__device__ __forceinline__ void do_mfx(
    const f16* __restrict__ xts, const half8 (&bf)[7][2],
    const floatx4& zacc, floatx4 (&acc)[2], int m)
{
    const int ar = MS * 16 + m;
    half8 a = *(const half8*)(xts + ar * 8);
    acc[0] = __builtin_amdgcn_mfma_f32_16x16x32_f16(a, bf[6][0], zacc, 0, 0, 0);
    acc[1] = __builtin_amdgcn_mfma_f32_16x16x32_f16(a, bf[6][1], zacc, 0, 0, 0);
}

// h-part: 12 MFMA cluster (setprio dropped — measured ~2 us negative here).
template <int MS>
__device__ __forceinline__ void do_mfh(
    const f16* __restrict__ hrd, const half8 (&bf)[7][2],
    floatx4 (&acc)[2], int m, int kg)
{
    const int ar = MS * 16 + m;
#pragma unroll
    for (int kt = 0; kt < 6; ++kt) {
        half8 a = *(const half8*)(hrd + hadr(ar + (kt >> 1), (kt & 1) * 4 + kg));
        acc[0] = __builtin_amdgcn_mfma_f32_16x16x32_f16(a, bf[kt][0], acc[0], 0, 0, 0);
        acc[1] = __builtin_amdgcn_mfma_f32_16x16x32_f16(a, bf[kt][1], acc[1], 0, 0, 0);
    }
}

// ---------------------------------------------------------------------------
// Single-tile epilogue (R21/R22 instruction diet):
//  - 8x two-operand update_dpp gate selects (1 op each + <=1 copy; was
//    cndmask+dpp+2 cndmask per (q,j))
//  - batched 8 independent v_exp (R16)
//  - rcp-fusion (R15): 7 trans/element
//  - fmaf(Fo,Ec,Fo) folds the h denominator
//  - all-lane ds_write_b16 h-write with hoisted swizzle offsets (was
//    dpp_xor1+pkrtz+even-lane dword); RTNE rounding (was RTZ)
// Pair (lane, lane^8): low lane owns rows rbase+j with rbase=kg*4, high lane
// rows rbase+j with rbase=kg*4+2. Gate registers per pair:
//   i: low own acc[0][j],  high from partner acc[0][2+j]  -> sel2<0xC>
//   f: high own acc[0][2+j], low from partner acc[0][j]   -> sel2<0x3>
//   o/g: same with acc[1].
// ---------------------------------------------------------------------------
template <int MS>
__device__ __forceinline__ void do_epi(
    f16* __restrict__ hwr, floatx4 (&acc)[2], float (&creg)[NMS * 2],
    int rbase, int ch0, int ch1, bool edge, int n0)
{
    // gate pre-activations, both elements: [j][i,f,o,g]
    float Y[2][4];
#pragma unroll
    for (int j = 0; j < 2; ++j) {
        Y[j][0] = sel2<0xC>(acc[0][j],     acc[0][2 + j]);   // i
        Y[j][1] = sel2<0x3>(acc[0][2 + j], acc[0][j]);       // f
        Y[j][2] = sel2<0xC>(acc[1][j],     acc[1][2 + j]);   // o
        Y[j][3] = sel2<0x3>(acc[1][2 + j], acc[1][j]);       // g
    }
    // 8 independent exps back-to-back (trans pipe fill)
    float E[2][4];
#pragma unroll
    for (int j = 0; j < 2; ++j)
#pragma unroll
        for (int g = 0; g < 4; ++g) E[j][g] = fast_exp2(Y[j][g]);

#pragma unroll
    for (int j = 0; j < 2; ++j) {
        float Fi = 1.0f + E[j][0], Ff = 1.0f + E[j][1];
        float Fo = 1.0f + E[j][2], Fg = 1.0f + E[j][3];
        const int ridx = MS * 2 + j;
        float P  = Fi * Fg;
        float N  = fmaf(E[j][3] - 1.0f, Ff, creg[ridx] * P);
        float cn = N * fast_rcp(P * Ff);          // sig(f)*c + sig(i)*tanh(g)
        float Ec = fast_exp2(cn * (2.0f * LOG2E));
        float hnf = (Ec - 1.0f) * fast_rcp(fmaf(Fo, Ec, Fo)); // sig(o)*tanh(cn)
        creg[ridx] = cn;
        int rit = MS * 16 + rbase + j;         // compute-window row
        if (edge) {
            int pos = n0 - HALO + rit;
            if (pos < 0 || pos >= NNP) hnf = 0.0f;  // zero-pad semantics
        }
        hwr[(rit + 1) * 64 + (j ? ch1 : ch0)] = (f16)hnf;   // all-lane b16
    }
}

// ---------------------------------------------------------------------------
// ConvLSTM, ALL 16 steps in ONE launch (R18), 512 independent blocks.
// Block = 512 thr (8 waves). Gate-packed MFMA N-dim (R9); halo-16 recompute;
// c in registers; fc fused into the drain; x staged in LDS 8 steps at a time
// (R19 showed global-x regresses). R20 trims: step 0 x-only; step 15 tiles
// 1..8 only; halo-row-only LDS init. R21-R23: epilogue VALU diet (two-operand
// update_dpp selects, b16 h-write, fma fold). Kernel is VALU-issue-bound
// (R20: MFMA/DS cuts don't move the wall, instruction count does).
// R17 lesson: occupancy is VGPR-capped; launch_bounds(512,2), stay <128 VGPR.
// ---------------------------------------------------------------------------
__global__ __launch_bounds__(512, 2)
void lstm_kernel(const float* __restrict__ x, const f16* __restrict__ wpack,
                 const float* __restrict__ fc_w, const float* __restrict__ fc_b,
                 float* __restrict__ out)
{
    __shared__ __align__(16) f16 hlds[2][HROWS * 64];
    __shared__ __align__(16) f16 xt[8 * WCMP * 8];

    const int blk  = blockIdx.x;
    const int b    = blk >> 5;
    const int tau  = blk & 31;
    const int n0   = tau * WOUT;
    const int tid  = threadIdx.x;
    const int lane = tid & 63;
    const int wave = tid >> 6;             // 0..7
    const int m    = lane & 15;
    const int kg   = lane >> 4;
    const int gh   = m >> 3;               // gate half of this lane's column
    const int hid  = wave * 8 + (m & 7);
    const bool edge = (tau == 0) || (tau == NTIL - 1);

    // epilogue row/address constants: this lane's two rows per tile are
    // rbase+j (j=0,1); h-write chunk offsets are MS-invariant (16 = 0 mod 8).
    const int rbase = kg * 4 + ((m < 8) ? 0 : 2);
    const int ch0 = ((wave ^ ((rbase + 1) & 7)) << 3) + (m & 7);
    const int ch1 = ((wave ^ ((rbase + 2) & 7)) << 3) + (m & 7);

    // B fragments, gate-packed: 14 half8 = 56 VGPR, resident all 16 steps.
    half8 bf[7][2];
#pragma unroll
    for (int kt = 0; kt < 7; ++kt)
#pragma unroll
        for (int q = 0; q < 2; ++q)
            bf[kt][q] = *(const half8*)(wpack + (size_t)((q * 2 + gh) * 64 + hid) * KPK + kt * 32 + kg * 8);

    const floatx4 zacc = {0.0f, 0.0f, 0.0f, 0.0f};   // persistent MFMA C seed

    float creg[NMS * 2];
#pragma unroll
    for (int i = 0; i < NMS * 2; ++i) creg[i] = 0.0f;

    // ---- stage 8 steps of x into xt (slot3 = 1.0 pairs with bias) ----
    auto stage_x = [&](int base) {
        for (int i = tid; i < 8 * WCMP; i += 512) {
            int ss = i / WCMP, r = i - ss * WCMP;
            const float* xb = x + ((size_t)b * TSN + base + ss) * NNP;
            int p = n0 - HALO + r;
            float v0 = (p - 1 >= 0 && p - 1 < NNP) ? xb[p - 1] : 0.0f;
            float v1 = (p >= 0 && p < NNP) ? xb[p] : 0.0f;
            float v2 = (p + 1 >= 0 && p + 1 < NNP) ? xb[p + 1] : 0.0f;
            unsigned* q = (unsigned*)(xt + (size_t)i * 8);
            q[0] = f16pair(v0, v1);
            q[1] = f16pair(v2, 1.0f);
            q[2] = 0u; q[3] = 0u;
        }
    };
    stage_x(0);

    // Only the conv-halo rows (0 and HROWS-1) of both buffers need zeroing —
    // every other read row is written by the preceding step (R20).
    for (int i = tid; i < 4 * 64; i += 512) {
        int buf = i >> 7, rr = ((i >> 6) & 1) ? (HROWS - 1) : 0;
        hlds[buf][rr * 64 + (i & 63)] = (f16)0;
    }

    __syncthreads();   // staging + halo-init visible to step 0

    // ---- step 0: x-only (h(0)=0 => gates = W_x*x + b), writes hlds[1] ----
    {
        f16* hwr = hlds[1];
        const f16* xts = xt;
        floatx4 accA[2], accB[2];
#define MFX(MS, A) do_mfx<MS>(xts, bf, zacc, A, m)
#define EP(MS, A)  do_epi<MS>(hwr, A, creg, rbase, ch0, ch1, edge, n0)
        MFX(0, accA);
        MFX(1, accB); EP(0, accA);
        MFX(2, accA); EP(1, accB);
        MFX(3, accB); EP(2, accA);
        MFX(4, accA); EP(3, accB);
        MFX(5, accB); EP(4, accA);
        MFX(6, accA); EP(5, accB);
        MFX(7, accB); EP(6, accA);
        MFX(8, accA); EP(7, accB);
        MFX(9, accB); EP(8, accA);
        EP(9, accB);
#undef MFX
#undef EP
    }

#pragma unroll 1
    for (int s = 1; s < TSN - 1; ++s) {
        if (s == 8) {
            __syncthreads();   // all step-7 xt reads complete before overwrite
            stage_x(8);
        }
        __syncthreads();   // step s's h reads vs step s-1's h writes (+ restage)

        const f16* hrd = hlds[s & 1];
        f16*       hwr = hlds[(s & 1) ^ 1];
        const f16* xts = xt + (size_t)(s & 7) * WCMP * 8;

        floatx4 accA[2], accB[2];
#define MFF(MS, A) do { do_mfx<MS>(xts, bf, zacc, A, m); do_mfh<MS>(hrd, bf, A, m, kg); } while (0)
#define EP(MS, A)  do_epi<MS>(hwr, A, creg, rbase, ch0, ch1, edge, n0)
        if (wave < 4) {
            MFF(0, accA);
            MFF(1, accB); EP(0, accA);
            MFF(2, accA); EP(1, accB);
            MFF(3, accB); EP(2, accA);
            MFF(4, accA); EP(3, accB);
            MFF(5, accB); EP(4, accA);
            MFF(6, accA); EP(5, accB);
            MFF(7, accB); EP(6, accA);
            MFF(8, accA); EP(7, accB);
            MFF(9, accB); EP(8, accA);
            EP(9, accB);
        } else {
            MFF(5, accA);
            MFF(6, accB); EP(5, accA);
            MFF(7, accA); EP(6, accB);
            MFF(8, accB); EP(7, accA);
            MFF(9, accA); EP(8, accB);
            MFF(0, accB); EP(9, accA);
            MFF(1, accA); EP(0, accB);
            MFF(2, accB); EP(1, accA);
            MFF(3, accA); EP(2, accB);
            MFF(4, accB); EP(3, accA);
            EP(4, accB);
        }
#undef MFF
#undef EP
    }

    // ---- step 15: only tiles 1..8 (output window rit in [16,144)) ----
    {
        __syncthreads();   // step-15 reads (hlds[1]) vs step-14 writes
        const f16* hrd = hlds[1];
        f16*       hwr = hlds[0];
        const f16* xts = xt + (size_t)7 * WCMP * 8;

        floatx4 accA[2], accB[2];
#define MFF(MS, A) do { do_mfx<MS>(xts, bf, zacc, A, m); do_mfh<MS>(hrd, bf, A, m, kg); } while (0)
#define EP(MS, A)  do_epi<MS>(hwr, A, creg, rbase, ch0, ch1, edge, n0)
        if (wave < 4) {
            MFF(1, accA);
            MFF(2, accB); EP(1, accA);
            MFF(3, accA); EP(2, accB);
            MFF(4, accB); EP(3, accA);
            MFF(5, accA); EP(4, accB);
            MFF(6, accB); EP(5, accA);
            MFF(7, accA); EP(6, accB);
            MFF(8, accB); EP(7, accA);
            EP(8, accB);
        } else {
            MFF(5, accA);
            MFF(6, accB); EP(5, accA);
            MFF(7, accA); EP(6, accB);
            MFF(8, accB); EP(7, accA);
            MFF(1, accA); EP(8, accB);
            MFF(2, accB); EP(1, accA);
            MFF(3, accA); EP(2, accB);
            MFF(4, accB); EP(3, accA);
            EP(4, accB);
        }
#undef MFF
#undef EP
    }
    __syncthreads();   // step-15 h writes complete (write buffer = hlds[0])

    // ---- fused fc drain: out[b,t,n0+row] = dot(h[row,:], fc_w) + fc_b ----
    // 4 threads per row, 16 hid each; shuffle-reduce; LDS bounce for coalesced
    // stores (xt is dead — reuse as float scratch).
    {
        const int part = tid & 3, row = tid >> 2;      // row in [0,128)
        float fw[16];
#pragma unroll
        for (int e = 0; e < 16; ++e) fw[e] = fc_w[part * 16 + e];
        const int rr = row + HALO + 1;                 // valid window row
        float ssum = 0.0f;
#pragma unroll
        for (int cc = 0; cc < 2; ++cc) {
            half8 v = *(const half8*)(hlds[0] + hadr(rr, part * 2 + cc));
#pragma unroll
            for (int e = 0; e < 8; ++e) ssum += (float)v[e] * fw[cc * 8 + e];
        }
        ssum += __shfl_xor(ssum, 1);
        ssum += __shfl_xor(ssum, 2);
        float* srow = (float*)xt;
        if (part == 0) srow[row] = ssum + fc_b[0];
        __syncthreads();
        for (int i = tid; i < WOUT * TSN; i += 512) {
            int tt = i >> 7, r2 = i & (WOUT - 1);
            out[((size_t)b * TSN + tt) * NNP + n0 + r2] = srow[r2];
        }
    }
}

extern "C" void kernel_launch(void* const* d_in, const int* in_sizes, int n_in,
                              void* d_out, int out_size, void* d_ws, size_t ws_size,
                              hipStream_t stream) {
    const float* x      = (const float*)d_in[0];
    const float* conv_w = (const float*)d_in[1];
    const float* conv_b = (const float*)d_in[2];
    const float* fc_w   = (const float*)d_in[3];
    const float* fc_b   = (const float*)d_in[4];
    float* out = (float*)d_out;

    f16* wpack = (f16*)d_ws;                                        // 112 KiB

    pack_w_kernel<<<(4 * 64 * KPK + 255) / 256, 256, 0, stream>>>(conv_w, conv_b, wpack);
    lstm_kernel<<<BB * NTIL, 512, 0, stream>>>(x, wpack, fc_w, fc_b, out);
}